// Round 2
// baseline (173.481 us; speedup 1.0000x reference)
//
#include <hip/hip_runtime.h>
#include <math.h>

// QMIX mixing network, B=65536, A=8, S=256, E=32. All tensors fp32.
// GEMM: bf16(states)[B,256] @ bf16(Wcat)[256,352] via mfma_f32_16x16x32_bf16,
// fp32 accumulate, fused epilogue.
// Wcat columns: [0,256)=w1_W, [256,288)=wf_W, [288,320)=b1_W, [320,352)=v1_W.

#define NTILES 22      // 352/16
#define KCHUNKS 8      // 256/32
#define BPERKC 11264   // 22*64*8 bf16 elements per k-chunk of repacked B

typedef __attribute__((ext_vector_type(8))) short short8;
typedef __attribute__((ext_vector_type(4))) short short4v;
typedef __attribute__((ext_vector_type(4))) float float4v;
typedef __attribute__((ext_vector_type(4))) int int4v;

__device__ __forceinline__ unsigned short f2b(float f) {
    unsigned int u = __float_as_uint(f);
    u = u + 0x7fffu + ((u >> 16) & 1u);   // RNE
    return (unsigned short)(u >> 16);
}

// Repack fp32 Wcat into bf16 MFMA B-fragment order: brep[kc][tile][lane][j] =
// bf16(W[k = kc*32 + (lane>>4)*8 + j][n = tile*16 + (lane&15)])
__global__ void repack_b(const float* __restrict__ w1_W,
                         const float* __restrict__ wf_W,
                         const float* __restrict__ b1_W,
                         const float* __restrict__ v1_W,
                         unsigned short* __restrict__ brep) {
    int idx = blockIdx.x * 256 + threadIdx.x;   // 0..90111
    int j    = idx & 7;
    int lane = (idx >> 3) & 63;
    int tt   = idx >> 9;          // 0..175 = kc*22 + tile
    int tile = tt % 22;
    int kc   = tt / 22;
    int k = kc * 32 + (lane >> 4) * 8 + j;
    int n = tile * 16 + (lane & 15);
    float val;
    if (n < 256)      val = w1_W[k * 256 + n];
    else if (n < 288) val = wf_W[k * 32 + (n - 256)];
    else if (n < 320) val = b1_W[k * 32 + (n - 288)];
    else              val = v1_W[k * 32 + (n - 320)];
    brep[idx] = f2b(val);
}

__launch_bounds__(256)
__global__ void qmix_main(const float* __restrict__ agent_qs,
                          const float* __restrict__ states,
                          const unsigned short* __restrict__ brep,
                          const float* __restrict__ w1_b,
                          const float* __restrict__ wf_b,
                          const float* __restrict__ b1_b,
                          const float* __restrict__ v1_b,
                          const float* __restrict__ v2_W,
                          const float* __restrict__ v2_b,
                          float* __restrict__ out) {
    // A tile: 64 rows x 256 k, bf16, row stride 264 (+8 pad -> spread banks)
    __shared__ __align__(16) unsigned short a_lds[64 * 264];
    // B k-chunk: 22 tiles x 64 lanes x 8 = 11264 bf16 (22528 B); reused as epilogue dump
    __shared__ __align__(16) unsigned short b_lds[BPERKC];

    const int tid  = threadIdx.x;
    const int wave = tid >> 6, lane = tid & 63;
    const int quad = lane >> 4, l16 = lane & 15;
    const int rowBase = blockIdx.x * 64;

    // ---- Stage A: 64 rows x 256 fp32 -> bf16 in LDS. 4096 float4 chunks. ----
    {
        const float4v* src = (const float4v*)(states + (size_t)rowBase * 256);
#pragma unroll
        for (int i = 0; i < 16; ++i) {
            int chunk = tid + i * 256;        // 0..4095
            int r = chunk >> 6, c4 = chunk & 63;   // row, 4-float group
            float4v v = src[r * 64 + c4];
            short4v b;
#pragma unroll
            for (int j = 0; j < 4; ++j) b[j] = (short)f2b(v[j]);
            *(short4v*)(&a_lds[r * 264 + c4 * 4]) = b;
        }
    }

    float4v acc[NTILES];
#pragma unroll
    for (int t = 0; t < NTILES; ++t)
#pragma unroll
        for (int q = 0; q < 4; ++q) acc[t][q] = 0.f;

    // ---- K loop ----
    for (int kc = 0; kc < KCHUNKS; ++kc) {
        __syncthreads();   // kc=0: A staged; kc>0: prev B reads done (WAR)
        {
            const int4v* src = (const int4v*)(brep + kc * BPERKC);
            int4v* dst = (int4v*)b_lds;
#pragma unroll
            for (int i = 0; i < 6; ++i) {
                int chunk = tid + i * 256;
                if (chunk < 1408) dst[chunk] = src[chunk];
            }
        }
        __syncthreads();
        // A fragment: A[m = l16][k = kc*32 + quad*8 + j], contiguous 16B in LDS
        short8 afrag = *(const short8*)(&a_lds[(wave * 16 + l16) * 264 + kc * 32 + quad * 8]);
#pragma unroll
        for (int t = 0; t < NTILES; ++t) {
            short8 bfrag = *(const short8*)(&b_lds[t * 512 + lane * 8]);
            acc[t] = __builtin_amdgcn_mfma_f32_16x16x32_bf16(afrag, bfrag, acc[t], 0, 0, 0);
        }
    }

    // ---- Epilogue ----
    __syncthreads();                       // all waves' MFMA B-reads done; b_lds reusable
    float* dump = (float*)b_lds + wave * 320;   // 16 rows x 20 floats (pad to 20)
    const int r = lane >> 2, p = lane & 3;      // 4 lanes cooperate per output row
    const int row = rowBase + wave * 16 + r;

    float qacc[8], wfv[8], b1v[8], svp = 0.f;
#pragma unroll
    for (int s = 0; s < 8; ++s) qacc[s] = 0.f;

#pragma unroll
    for (int t = 0; t < NTILES; ++t) {
        // D layout: col = lane&15, row = quad*4 + reg  (m89/m91 verified)
#pragma unroll
        for (int reg = 0; reg < 4; ++reg)
            dump[(quad * 4 + reg) * 20 + l16] = acc[t][reg];
        __threadfence_block();                 // lgkmcnt(0) + compiler barrier
        float4v v = *(const float4v*)(&dump[r * 20 + p * 4]);

        const float* bptr =
            (t < 16) ? (w1_b + t * 16) :
            (t < 18) ? (wf_b + (t - 16) * 16) :
            (t < 20) ? (b1_b + (t - 18) * 16) : (v1_b + (t - 20) * 16);
        float vb[4];
#pragma unroll
        for (int j = 0; j < 4; ++j) vb[j] = v[j] + bptr[p * 4 + j];

        if (t < 16) {              // w1 region: col = a*32 + e; a = t>>1, e = (t&1)*16 + p*4 + j
            float q = agent_qs[row * 8 + (t >> 1)];
            int base = (t & 1) * 4;
#pragma unroll
            for (int j = 0; j < 4; ++j) qacc[base + j] += q * fabsf(vb[j]);
        } else if (t < 18) {       // w_final
            int base = (t - 16) * 4;
#pragma unroll
            for (int j = 0; j < 4; ++j) wfv[base + j] = fabsf(vb[j]);
        } else if (t < 20) {       // b1
            int base = (t - 18) * 4;
#pragma unroll
            for (int j = 0; j < 4; ++j) b1v[base + j] = vb[j];
        } else {                   // V hidden: relu -> dot v2_W
            int ebase = (t - 20) * 16 + p * 4;
#pragma unroll
            for (int j = 0; j < 4; ++j)
                svp += fmaxf(vb[j], 0.f) * v2_W[ebase + j];
        }
        __threadfence_block();                 // reads done before next tile's writes
    }

    float m = 0.f;
#pragma unroll
    for (int s = 0; s < 8; ++s) {
        float h = qacc[s] + b1v[s];
        h = h > 0.f ? h : expm1f(h);           // elu, alpha=1
        m += h * wfv[s];
    }
    float tot = m + svp;
    tot += __shfl_xor(tot, 1);                 // sum over the 4 cooperating lanes
    tot += __shfl_xor(tot, 2);
    if (p == 0) out[row] = tot + v2_b[0];
}

extern "C" void kernel_launch(void* const* d_in, const int* in_sizes, int n_in,
                              void* d_out, int out_size, void* d_ws, size_t ws_size,
                              hipStream_t stream) {
    const float* agent_qs = (const float*)d_in[0];
    const float* states   = (const float*)d_in[1];
    const float* w1_W = (const float*)d_in[2];
    const float* w1_b = (const float*)d_in[3];
    const float* wf_W = (const float*)d_in[4];
    const float* wf_b = (const float*)d_in[5];
    const float* b1_W = (const float*)d_in[6];
    const float* b1_b = (const float*)d_in[7];
    const float* v1_W = (const float*)d_in[8];
    const float* v1_b = (const float*)d_in[9];
    const float* v2_W = (const float*)d_in[10];
    const float* v2_b = (const float*)d_in[11];
    float* out = (float*)d_out;
    unsigned short* brep = (unsigned short*)d_ws;    // 180224 B of scratch

    repack_b<<<352, 256, 0, stream>>>(w1_W, wf_W, b1_W, v1_W, brep);
    qmix_main<<<1024, 256, 0, stream>>>(agent_qs, states, brep,
                                        w1_b, wf_b, b1_b, v1_b, v2_W, v2_b, out);
}